// Round 7
// baseline (222.596 us; speedup 1.0000x reference)
//
#include <hip/hip_runtime.h>

constexpr int H = 2048, W = 2048, HW = H * W, MASK = 2047;
constexpr float TEMP = 0.1f;
constexpr float EPS = 1e-8f;
constexpr float SQ2 = 0.70710678118654752440f;
constexpr int NACC = 128;   // accumulator slots per sum, one cache line each

// ---------------------------------------------------------------------------
// Fused kernel, 16x16 interior tile per 256-thread block.
// vs round 6 (94us, VALU 57%, ~41us stall):
//  * phase-2 global operands (m, fx, fy, mx, my for both t-iterations) are
//    prefetched into registers BEFORE the phase-1 barrier: mom is cold
//    (~900cyc HBM) and the compiler can't hoist loads across __syncthreads.
//    Overlaps that latency with phase-1 LDS writes + barrier drain.
//  * phase-3 gather uses fmaf (outputs not 1/mass-amplified; ~1e-7 effect).
//  * conv / force / velocity / logit chain stays strict __f*_rn — that path
//    is amplified ~1e6x at near-dead cells; preserves the passing 0.0156 draw.
// ---------------------------------------------------------------------------
__global__ __launch_bounds__(256) void k_main(
    const float* __restrict__ mass, const float* __restrict__ mom,
    const float* __restrict__ force, const float* __restrict__ A,
    const float* __restrict__ ker,
    float* __restrict__ out,            // [nm | mom_x | mom_y | f_x | f_y]
    double* __restrict__ acc)           // [NACC*8 for mass | NACC*8 for nm]
{
    __shared__ float XS[20 * 24];
    __shared__ float MS[324], PMX[324], PMY[324];
    __shared__ float PR[9][324];
    __shared__ float KS[36];
    __shared__ float wsum0[4], wsum1[4];

    const int tid = threadIdx.x;
    // XCD-aware tile mapping: xcd = b&7 owns tile rows [xcd*16, xcd*16+16)
    const int b = blockIdx.x;
    const int xcd = b & 7, r = b >> 3;
    const int by = (xcd << 4) | (r >> 7), bx = r & 127;
    const int gx0 = bx << 4, gy0 = by << 4;

    if (tid < 36) KS[tid] = ker[tid];

    // ---- prefetch phase-2 operands (issued earliest; mom is cold) ----
    const int t0 = tid, t1 = tid + 256;
    const int ly0 = t0 / 18, lx0 = t0 - ly0 * 18;
    const int idx0 = (((gy0 + ly0 - 1) & MASK) << 11) | ((gx0 + lx0 - 1) & MASK);
    const float m0  = mass[idx0];
    const float mx0 = mom[idx0],   my0 = mom[idx0 + HW];
    const float fx0 = force[idx0], fy0 = force[idx0 + HW];
    float m1 = 0.f, mx1 = 0.f, my1 = 0.f, fx1 = 0.f, fy1 = 0.f;
    int idx1 = 0;
    if (tid < 68) {
        const int ly1 = t1 / 18, lx1 = t1 - ly1 * 18;
        idx1 = (((gy0 + ly1 - 1) & MASK) << 11) | ((gx0 + lx1 - 1) & MASK);
        m1  = mass[idx1];
        mx1 = mom[idx1];   my1 = mom[idx1 + HW];
        fx1 = force[idx1]; fy1 = force[idx1 + HW];
    }

    // ---- phase 1: stage X on 20x24 halo, float2 loads ----
    if (tid < 240) {
        const int py = tid / 12, px2 = (tid - py * 12) * 2;   // col pair 0..22
        const int gy = (gy0 + py - 2) & MASK;
        const int gxp = (gx0 + px2 - 4) & MASK;               // even, no row cross
        const int idx = gy * W + gxp;
        const float2 m2 = *(const float2*)(mass + idx);
        const float2 a2 = *(const float2*)(A + idx);
        const float2 fx2 = *(const float2*)(force + idx);
        const float2 fy2 = *(const float2*)(force + HW + idx);
        float x0 = __fadd_rn(__fmul_rn(a2.x, m2.x),
            __fsqrt_rn(__fadd_rn(__fmul_rn(fx2.x, fx2.x), __fmul_rn(fy2.x, fy2.x))));
        float x1 = __fadd_rn(__fmul_rn(a2.y, m2.y),
            __fsqrt_rn(__fadd_rn(__fmul_rn(fx2.y, fx2.y), __fmul_rn(fy2.y, fy2.y))));
        *(float2*)&XS[py * 24 + px2] = make_float2(x0, x1);
    }
    __syncthreads();

    float ksum = 0.f;
#pragma unroll
    for (int i = 0; i < 36; ++i) ksum = __fadd_rn(ksum, fabsf(KS[i]));
    const float kc = 1.0f / ksum;

    const float D0[9] = {SQ2, 0.f, -SQ2, 1.f, 0.f, -1.f, SQ2, 0.f, -SQ2};
    const float D1[9] = {SQ2, 1.f, SQ2, 0.f, 0.f, 0.f, -SQ2, -1.f, -SQ2};

    // ---- phase 2: per 18x18 ring cell (operands pre-loaded) ----
    auto cell = [&](int t, float m, float fx, float fy, float mx, float my) {
        const int ly = t / 18, lx = t - ly * 18;
        float nf0 = 0.f, nf1 = 0.f, nf2 = 0.f, nf3 = 0.f;
#pragma unroll
        for (int ky = 0; ky < 3; ++ky)
#pragma unroll
            for (int kx = 0; kx < 3; ++kx) {
                const float x = XS[(ly + ky) * 24 + lx + kx + 2];
                const int j = ky * 3 + kx;
                nf0 = __fadd_rn(nf0, __fmul_rn(KS[j],      x));
                nf1 = __fadd_rn(nf1, __fmul_rn(KS[9 + j],  x));
                nf2 = __fadd_rn(nf2, __fmul_rn(KS[18 + j], x));
                nf3 = __fadd_rn(nf3, __fmul_rn(KS[27 + j], x));
            }
        const float nfx = __fadd_rn(nf0, nf1);                     // sum
        const float nfy = __fmul_rn(__fadd_rn(nf2, nf3), 0.5f);    // mean
        const float fnx = __fadd_rn(fx, __fmul_rn(__fsub_rn(nfx, fx), kc));
        const float fny = __fadd_rn(fy, __fmul_rn(__fsub_rn(nfy, fy), kc));
        const bool dead = m < EPS;
        const float pmx = dead ? 0.f : __fadd_rn(mx, fnx);         // DT = 1
        const float pmy = dead ? 0.f : __fadd_rn(my, fny);
        MS[t] = m; PMX[t] = pmx; PMY[t] = pmy;
        const float vx = dead ? 0.f : pmx / m;
        const float vy = dead ? 0.f : pmy / m;
        float l[9], lmax = -1e30f;
#pragma unroll
        for (int d = 0; d < 9; ++d) {
            l[d] = __fmul_rn(__fadd_rn(__fmul_rn(D0[d], vx),
                                       __fmul_rn(D1[d], vy)), TEMP);
            lmax = fmaxf(lmax, l[d]);
        }
        float e[9], esum = 0.f;
#pragma unroll
        for (int d = 0; d < 9; ++d) {
            e[d] = __expf(__fsub_rn(l[d], lmax));   // native v_exp_f32
            esum = __fadd_rn(esum, e[d]);
        }
        const float inv = 1.0f / esum;
#pragma unroll
        for (int d = 0; d < 9; ++d) PR[d][t] = __fmul_rn(e[d], inv);

        if (ly >= 1 && ly <= 16 && lx >= 1 && lx <= 16) {          // interior
            const int gidx = (gy0 + ly - 1) * W + gx0 + lx - 1;
            out[3 * HW + gidx] = fnx;
            out[4 * HW + gidx] = fny;
        }
    };
    cell(t0, m0, fx0, fy0, mx0, my0);
    if (tid < 68) cell(t1, m1, fx1, fy1, mx1, my1);
    __syncthreads();

    // ---- phase 3: gather for 16x16 interior (fmaf safe: not amplified) ----
    const int tx = tid & 15, ty = tid >> 4;
    float nm = 0.f, omx = 0.f, omy = 0.f;
#pragma unroll
    for (int d = 0; d < 9; ++d) {
        const int dy = 1 - d / 3, dx = 1 - d % 3;                  // MOVES shift
        const int n = (ty + 1 + dy) * 18 + tx + 1 + dx;
        const float p = PR[d][n];
        nm  = fmaf(MS[n],  p, nm);
        omx = fmaf(PMX[n], p, omx);
        omy = fmaf(PMY[n], p, omy);
    }
    const int gidx = (gy0 + ty) * W + gx0 + tx;
    out[gidx]          = nm;                                       // unnormalized
    out[HW + gidx]     = omx;
    out[2 * HW + gidx] = omy;

    // ---- block reductions -> line-spread f64 accumulators ----
    float s0 = MS[(ty + 1) * 18 + tx + 1];                         // own mass
    float s1 = nm;
#pragma unroll
    for (int off = 32; off > 0; off >>= 1) {
        s0 += __shfl_down(s0, off);
        s1 += __shfl_down(s1, off);
    }
    if ((tid & 63) == 0) { wsum0[tid >> 6] = s0; wsum1[tid >> 6] = s1; }
    __syncthreads();
    if (tid == 0) {
        const int slot = (blockIdx.x & (NACC - 1)) * 8;            // own line
        atomicAdd(acc + slot,
                  (double)(wsum0[0] + wsum0[1] + wsum0[2] + wsum0[3]));
        atomicAdd(acc + NACC * 8 + slot,
                  (double)(wsum1[0] + wsum1[1] + wsum1[2] + wsum1[3]));
    }
}

// ---------------------------------------------------------------------------
// Rescale: reduce the 2*NACC partials in-register (lane-parallel + shuffle),
// then new_mass = mass_tot * new_mass / sum(new_mass), in place, float4.
// ---------------------------------------------------------------------------
__global__ __launch_bounds__(256) void k_norm(
    float* __restrict__ nm, const double* __restrict__ acc)
{
    const int lane = threadIdx.x & 63;
    double s0 = 0.0, s1 = 0.0;
#pragma unroll
    for (int i = 0; i < NACC / 64; ++i) {                // 2 slots per lane
        const int slot = (lane + i * 64) * 8;
        s0 += acc[slot];
        s1 += acc[NACC * 8 + slot];
    }
#pragma unroll
    for (int off = 32; off > 0; off >>= 1) {
        s0 += __shfl_down(s0, off);
        s1 += __shfl_down(s1, off);
    }
    const float mt  = (float)__shfl(s0, 0);
    const float snm = (float)__shfl(s1, 0);

    const int i = (blockIdx.x * 256 + threadIdx.x) * 4;
    float4 v = *(float4*)(nm + i);
    v.x = __fmul_rn(mt, v.x) / snm;
    v.y = __fmul_rn(mt, v.y) / snm;
    v.z = __fmul_rn(mt, v.z) / snm;
    v.w = __fmul_rn(mt, v.w) / snm;
    *(float4*)(nm + i) = v;
}

extern "C" void kernel_launch(void* const* d_in, const int* in_sizes, int n_in,
                              void* d_out, int out_size, void* d_ws, size_t ws_size,
                              hipStream_t stream)
{
    const float* mass  = (const float*)d_in[0];
    const float* mom   = (const float*)d_in[1];
    const float* force = (const float*)d_in[2];
    const float* A     = (const float*)d_in[3];
    const float* ker   = (const float*)d_in[4];
    float* out = (float*)d_out;

    double* acc = (double*)d_ws;                  // 2 * NACC * 8 doubles = 16 KiB
    hipMemsetAsync(acc, 0, 2 * NACC * 8 * sizeof(double), stream);

    k_main<<<dim3(128 * 128), dim3(256), 0, stream>>>(mass, mom, force, A, ker,
                                                      out, acc);
    k_norm<<<dim3(HW / 1024), dim3(256), 0, stream>>>(out, acc);
}

// Round 8
// 208.672 us; speedup vs baseline: 1.0667x; 1.0667x over previous
//
#include <hip/hip_runtime.h>

constexpr int H = 2048, W = 2048, HW = H * W, MASK = 2047;
constexpr float TEMP = 0.1f;
constexpr float EPS = 1e-8f;
constexpr float SQ2 = 0.70710678118654752440f;
constexpr int NACC = 128;   // accumulator slots per sum, one cache line each

// ---------------------------------------------------------------------------
// Fused kernel, 16x32 interior tile per 512-thread block (was 16x16/256).
// vs round 7 (94us, VALU 57%, issue-bound):
//  * ring/interior 612/512=1.20 (was 1.27); tail divergence 2-of-8 waves
//    (was 2-of-4): ~17% less phase-2 issue per output.
//  * logits restructured bit-exactly: the 9 dirs are {+-(s*vx+s*vy),
//    +-(s*vy-s*vx), +-vx, +-vy, 0}; IEEE rounding is sign-symmetric, so
//    4 muls + 2 adds + 4 muls reproduce np's einsum exactly (~28 inst/cell
//    saved). lmax = max of 4 absolutes.
//  * conv / force / velocity / divide chain stays strict __f*_rn (amplified
//    ~1/mass at near-dead cells; preserves the passing 0.0156 draw).
// ---------------------------------------------------------------------------
__global__ __launch_bounds__(512) void k_main(
    const float* __restrict__ mass, const float* __restrict__ mom,
    const float* __restrict__ force, const float* __restrict__ A,
    const float* __restrict__ ker,
    float* __restrict__ out,            // [nm | mom_x | mom_y | f_x | f_y]
    double* __restrict__ acc)           // [NACC*8 for mass | NACC*8 for nm]
{
    __shared__ float XS[20 * 40];                  // halo y:-2..17, x:-4..35
    __shared__ float MS[612], PMX[612], PMY[612];  // ring 18x34
    __shared__ float PR[9][612];
    __shared__ float KS[36];
    __shared__ float wsum0[8], wsum1[8];

    const int tid = threadIdx.x;
    // XCD-aware tile mapping: xcd = b&7 owns 16 consecutive tile rows
    const int b = blockIdx.x;                      // 8192 blocks: 128y x 64x
    const int xcd = b & 7, r = b >> 3;
    const int by = (xcd << 4) | (r >> 6), bx = r & 63;
    const int gx0 = bx << 5, gy0 = by << 4;

    if (tid < 36) KS[tid] = ker[tid];

    // ---- phase 1: stage X on 20x40 halo, float2 loads ----
    if (tid < 400) {
        const int py = tid / 20, px2 = (tid - py * 20) * 2;   // cols 0..38
        const int gy = (gy0 + py - 2) & MASK;
        const int gxp = (gx0 + px2 - 4) & MASK;               // even, no row cross
        const int idx = gy * W + gxp;
        const float2 m2 = *(const float2*)(mass + idx);
        const float2 a2 = *(const float2*)(A + idx);
        const float2 fx2 = *(const float2*)(force + idx);
        const float2 fy2 = *(const float2*)(force + HW + idx);
        float x0 = __fadd_rn(__fmul_rn(a2.x, m2.x),
            __fsqrt_rn(__fadd_rn(__fmul_rn(fx2.x, fx2.x), __fmul_rn(fy2.x, fy2.x))));
        float x1 = __fadd_rn(__fmul_rn(a2.y, m2.y),
            __fsqrt_rn(__fadd_rn(__fmul_rn(fx2.y, fx2.y), __fmul_rn(fy2.y, fy2.y))));
        *(float2*)&XS[py * 40 + px2] = make_float2(x0, x1);
    }
    __syncthreads();

    float ksum = 0.f;
#pragma unroll
    for (int i = 0; i < 36; ++i) ksum = __fadd_rn(ksum, fabsf(KS[i]));
    const float kc = 1.0f / ksum;

    // ---- phase 2: per 18x34 ring cell ----
    auto cell = [&](int t) {
        const int ly = t / 34, lx = t - ly * 34;
        const int idx = (((gy0 + ly - 1) & MASK) << 11) | ((gx0 + lx - 1) & MASK);
        const float m  = mass[idx];
        const float fx = force[idx], fy = force[idx + HW];
        const float mx = mom[idx],   my = mom[idx + HW];

        float nf0 = 0.f, nf1 = 0.f, nf2 = 0.f, nf3 = 0.f;
#pragma unroll
        for (int ky = 0; ky < 3; ++ky)
#pragma unroll
            for (int kx = 0; kx < 3; ++kx) {
                const float x = XS[(ly + ky) * 40 + lx + kx + 2];
                const int j = ky * 3 + kx;
                nf0 = __fadd_rn(nf0, __fmul_rn(KS[j],      x));
                nf1 = __fadd_rn(nf1, __fmul_rn(KS[9 + j],  x));
                nf2 = __fadd_rn(nf2, __fmul_rn(KS[18 + j], x));
                nf3 = __fadd_rn(nf3, __fmul_rn(KS[27 + j], x));
            }
        const float nfx = __fadd_rn(nf0, nf1);                     // sum
        const float nfy = __fmul_rn(__fadd_rn(nf2, nf3), 0.5f);    // mean
        const float fnx = __fadd_rn(fx, __fmul_rn(__fsub_rn(nfx, fx), kc));
        const float fny = __fadd_rn(fy, __fmul_rn(__fsub_rn(nfy, fy), kc));
        const bool dead = m < EPS;
        const float pmx = dead ? 0.f : __fadd_rn(mx, fnx);         // DT = 1
        const float pmy = dead ? 0.f : __fadd_rn(my, fny);
        MS[t] = m; PMX[t] = pmx; PMY[t] = pmy;
        const float vx = dead ? 0.f : pmx / m;
        const float vy = dead ? 0.f : pmy / m;

        // logits, bit-exact to np einsum (sign-symmetric IEEE rounding)
        const float p = __fmul_rn(SQ2, vx), q = __fmul_rn(SQ2, vy);
        const float l0 = __fmul_rn(__fadd_rn(p, q), TEMP);   // dir ( s, s)
        const float l1 = __fmul_rn(vy, TEMP);                // dir ( 0, 1)
        const float l2 = __fmul_rn(__fsub_rn(q, p), TEMP);   // dir (-s, s)
        const float l3 = __fmul_rn(vx, TEMP);                // dir ( 1, 0)
        const float lmax = fmaxf(fmaxf(fabsf(l0), fabsf(l1)),
                                 fmaxf(fabsf(l2), fmaxf(fabsf(l3), 0.f)));
        const float l[9] = {l0, l1, l2, l3, 0.f, -l3, -l2, -l1, -l0};
        float e[9], esum = 0.f;
#pragma unroll
        for (int d = 0; d < 9; ++d) {
            e[d] = __expf(__fsub_rn(l[d], lmax));   // native v_exp_f32
            esum = __fadd_rn(esum, e[d]);
        }
        const float inv = 1.0f / esum;
#pragma unroll
        for (int d = 0; d < 9; ++d) PR[d][t] = __fmul_rn(e[d], inv);

        if (ly >= 1 && ly <= 16 && lx >= 1 && lx <= 32) {          // interior
            const int gidx = (gy0 + ly - 1) * W + gx0 + lx - 1;
            out[3 * HW + gidx] = fnx;
            out[4 * HW + gidx] = fny;
        }
    };
    cell(tid);
    if (tid < 100) cell(tid + 512);
    __syncthreads();

    // ---- phase 3: gather for 16x32 interior (fmaf safe: not amplified) ----
    const int tx = tid & 31, ty = tid >> 5;
    float nm = 0.f, omx = 0.f, omy = 0.f;
#pragma unroll
    for (int d = 0; d < 9; ++d) {
        const int dy = 1 - d / 3, dx = 1 - d % 3;                  // MOVES shift
        const int n = (ty + 1 + dy) * 34 + tx + 1 + dx;
        const float p = PR[d][n];
        nm  = fmaf(MS[n],  p, nm);
        omx = fmaf(PMX[n], p, omx);
        omy = fmaf(PMY[n], p, omy);
    }
    const int gidx = (gy0 + ty) * W + gx0 + tx;
    out[gidx]          = nm;                                       // unnormalized
    out[HW + gidx]     = omx;
    out[2 * HW + gidx] = omy;

    // ---- block reductions -> line-spread f64 accumulators ----
    float s0 = MS[(ty + 1) * 34 + tx + 1];                         // own mass
    float s1 = nm;
#pragma unroll
    for (int off = 32; off > 0; off >>= 1) {
        s0 += __shfl_down(s0, off);
        s1 += __shfl_down(s1, off);
    }
    if ((tid & 63) == 0) { wsum0[tid >> 6] = s0; wsum1[tid >> 6] = s1; }
    __syncthreads();
    if (tid == 0) {
        float t0 = 0.f, t1 = 0.f;
#pragma unroll
        for (int i = 0; i < 8; ++i) { t0 += wsum0[i]; t1 += wsum1[i]; }
        const int slot = (blockIdx.x & (NACC - 1)) * 8;            // own line
        atomicAdd(acc + slot,            (double)t0);
        atomicAdd(acc + NACC * 8 + slot, (double)t1);
    }
}

// ---------------------------------------------------------------------------
// Rescale: reduce the 2*NACC partials in-register (lane-parallel + shuffle),
// then new_mass = mass_tot * new_mass / sum(new_mass), in place, float4.
// ---------------------------------------------------------------------------
__global__ __launch_bounds__(256) void k_norm(
    float* __restrict__ nm, const double* __restrict__ acc)
{
    const int lane = threadIdx.x & 63;
    double s0 = 0.0, s1 = 0.0;
#pragma unroll
    for (int i = 0; i < NACC / 64; ++i) {                // 2 slots per lane
        const int slot = (lane + i * 64) * 8;
        s0 += acc[slot];
        s1 += acc[NACC * 8 + slot];
    }
#pragma unroll
    for (int off = 32; off > 0; off >>= 1) {
        s0 += __shfl_down(s0, off);
        s1 += __shfl_down(s1, off);
    }
    const float mt  = (float)__shfl(s0, 0);
    const float snm = (float)__shfl(s1, 0);

    const int i = (blockIdx.x * 256 + threadIdx.x) * 4;
    float4 v = *(float4*)(nm + i);
    v.x = __fmul_rn(mt, v.x) / snm;
    v.y = __fmul_rn(mt, v.y) / snm;
    v.z = __fmul_rn(mt, v.z) / snm;
    v.w = __fmul_rn(mt, v.w) / snm;
    *(float4*)(nm + i) = v;
}

extern "C" void kernel_launch(void* const* d_in, const int* in_sizes, int n_in,
                              void* d_out, int out_size, void* d_ws, size_t ws_size,
                              hipStream_t stream)
{
    const float* mass  = (const float*)d_in[0];
    const float* mom   = (const float*)d_in[1];
    const float* force = (const float*)d_in[2];
    const float* A     = (const float*)d_in[3];
    const float* ker   = (const float*)d_in[4];
    float* out = (float*)d_out;

    double* acc = (double*)d_ws;                  // 2 * NACC * 8 doubles = 16 KiB
    hipMemsetAsync(acc, 0, 2 * NACC * 8 * sizeof(double), stream);

    k_main<<<dim3(8192), dim3(512), 0, stream>>>(mass, mom, force, A, ker,
                                                 out, acc);
    k_norm<<<dim3(HW / 1024), dim3(256), 0, stream>>>(out, acc);
}